// Round 4
// baseline (110.297 us; speedup 1.0000x reference)
//
#include <hip/hip_runtime.h>
#include <math.h>

#define POOLED      7
#define OUTPUT_DIM  21
#define GROUP       7
#define CHANNELS    (OUTPUT_DIM * GROUP * GROUP)   // 1029
#define FH          64
#define FW          64
#define PLANE       (FH * FW)                      // 4096 floats, 16 KB
#define NUM_ROIS    1024
#define SCALE       0.0625f

// Opaque VGPR pin: blocks FMA contraction (hipcc -ffp-contract=fast ignores
// `#pragma clang fp contract(off)`). CORRECTNESS-CRITICAL: the golden's
// boundary chain is f32, separately rounded, with bin = roi * RN(1/7)
// (reciprocal multiply) — verified round 10, absmax 3.9e-3. Do not change.
__device__ __forceinline__ float freeze(float x) {
    __asm__ volatile("" : "+v"(x));
    return x;
}

// ---- frozen boundary chain, value form (ops identical to r10-verified) ----
struct RoiGeom { int b; float start_h, start_w, bin_h, bin_w; };

__device__ __forceinline__ RoiGeom roi_geom_v(float r0, float r1, float r2,
                                              float r3, float r4) {
    RoiGeom g;
    g.b = (int)r0;
    float start_w = rintf(r1) * SCALE;            // np.round = half-even
    float start_h = rintf(r2) * SCALE;
    float end_w   = rintf(r3 + 1.0f) * SCALE;
    float end_h   = rintf(r4 + 1.0f) * SCALE;
    float roi_w = fmaxf(end_w - start_w, 0.1f);
    float roi_h = fmaxf(end_h - start_h, 0.1f);
    const float inv7 = 1.0f / 7.0f;               // RN(1/7)
    g.bin_h = freeze(roi_h * inv7);               // reciprocal multiply
    g.bin_w = freeze(roi_w * inv7);
    g.start_h = start_h;
    g.start_w = start_w;
    return g;
}

// ph/pw tail of the frozen chain -> clamped integer bounds (no LDS access).
__device__ __forceinline__ void bin_bounds(const RoiGeom& g, int ph, int pw,
                                           int& hs, int& he, int& ws, int& we) {
    float mh0 = freeze((float)ph * g.bin_h);      // separate mul, then add
    float mh1 = freeze((float)(ph + 1) * g.bin_h);
    float mw0 = freeze((float)pw * g.bin_w);
    float mw1 = freeze((float)(pw + 1) * g.bin_w);

    float hs_f = floorf(mh0 + g.start_h);
    float he_f = ceilf (mh1 + g.start_h);
    float ws_f = floorf(mw0 + g.start_w);
    float we_f = ceilf (mw1 + g.start_w);

    hs = (int)fminf(fmaxf(hs_f, 0.0f), (float)FH);
    he = (int)fminf(fmaxf(he_f, 0.0f), (float)FH);
    ws = (int)fminf(fmaxf(ws_f, 0.0f), (float)FW);
    we = (int)fminf(fmaxf(we_f, 0.0f), (float)FW);
}

__device__ __forceinline__ float region_avg(const float* __restrict__ plane,
                                            int hs, int he, int ws, int we) {
    float s = 0.0f;
    for (int h = hs; h < he; ++h) {
        const float* row = plane + h * FW;
        for (int w = ws; w < we; ++w) s += row[w];
    }
    int area = (he - hs) * (we - ws);
    return (area <= 0) ? 0.0f : s / (float)area;
}

// BATCH-BUCKETED BIN-MAJOR (round 15). R1/R3 structure was capped at
// 2 blocks/CU (64 KB LDS + 1024 thr) with a 2.01-round grid -> main kernel
// ~20 us vs a 10.7 us fetch floor. Here block = (channel c, batch b): each
// ROI reads exactly one batch plane, so the block stages ONE 16 KB plane.
// 256 threads, 16 KB LDS -> 8 blocks/CU, 4116 blocks, 4x the HBM streams,
// negligible tail. Fetch stays exactly-once per (b,c) plane.
//
// Write side: the block's ~256 ROIs (batch==b) are scattered in n, so we
// write bucket-compacted: every block deterministically computes the stable
// partition of ROIs by batch (ballot-free shfl scan, pure function of rois),
// writes ws[c][off_b + rank] contiguously (no RMW), and c==0 blocks emit
// perm[k]=n for the transpose. One barrier total (merged scan + stage drain).
__global__ __launch_bounds__(256, 8)
void psroi_bucket(const float* __restrict__ feat,
                  const float* __restrict__ rois,
                  float* __restrict__ ws,
                  int* __restrict__ perm) {
    const int bid = blockIdx.x;
    const int c   = bid >> 2;             // 0..1028
    const int b   = bid & 3;              // batch bucket
    const int pw  = c % 7;
    const int ph  = (c / 7) % 7;
    const int t   = threadIdx.x;          // 0..255
    const int ln  = t & 63;
    const int wv  = t >> 6;               // 0..3

    __shared__ float pl[PLANE];           // 16 KB: plane (b, c)
    __shared__ unsigned long long wsum[4];

    // 1. Load ROI data for n = 4t..4t+3 (all global reads BEFORE staging so
    //    in-order vmcnt retire never forces a drain of the staging loads).
    float rr[4][5];
#pragma unroll
    for (int j = 0; j < 4; ++j) {
        const float* r = rois + (size_t)(4 * t + j) * 5;
#pragma unroll
        for (int q = 0; q < 5; ++q) rr[j][q] = r[q];
    }

    int bj[4];
    int m[4] = {0, 0, 0, 0};
#pragma unroll
    for (int j = 0; j < 4; ++j) {
        bj[j] = ((int)rr[j][0]) & 3;      // batch in 0..3
        m[bj[j]]++;
    }

    // 2. Stable compaction scan (order = n ascending == (wave, lane, j)).
    //    Packed per-bucket counts, 16 bits each, one 64-bit wave reduce.
    unsigned long long pk =
        (unsigned long long)m[0]        | ((unsigned long long)m[1] << 16) |
        ((unsigned long long)m[2] << 32) | ((unsigned long long)m[3] << 48);
    unsigned long long red = pk;
#pragma unroll
    for (int d = 1; d < 64; d <<= 1) red += __shfl_xor(red, d, 64);

    int my  = m[b];
    int inc = my;                          // inclusive lane scan of my-bucket
#pragma unroll
    for (int d = 1; d < 64; d <<= 1) {
        int u = __shfl_up(inc, d, 64);
        if (ln >= d) inc += u;
    }
    if (ln == 0) wsum[wv] = red;           // per-wave packed totals -> LDS

    // 3. Geometry for matched ROIs now (register-only; rr dies here).
    int hs[4], he[4], wss[4], wee[4];
#pragma unroll
    for (int j = 0; j < 4; ++j) {
        hs[j] = 0; he[j] = 0; wss[j] = 0; wee[j] = 0;
        if (bj[j] == b) {
            RoiGeom g = roi_geom_v(rr[j][0], rr[j][1], rr[j][2], rr[j][3], rr[j][4]);
            bin_bounds(g, ph, pw, hs[j], he[j], wss[j], wee[j]);
        }
    }

    // 4. Stage plane (b, c): 4 iters x (256 lanes x 16 B) = 16 KB, coalesced,
    //    fire-and-forget into LDS (dest = wave-uniform base + lane*16).
#if defined(__has_builtin) && __has_builtin(__builtin_amdgcn_global_load_lds)
    typedef const void __attribute__((address_space(1)))* gas_t;
    typedef void __attribute__((address_space(3)))*       las_t;
    {
        const float* src0 = feat + ((size_t)b * CHANNELS + c) * PLANE + 4 * (size_t)t;
#pragma unroll
        for (int i = 0; i < 4; ++i) {
            __builtin_amdgcn_global_load_lds((gas_t)(src0 + i * 1024),
                                             (las_t)(pl + i * 1024 + 4 * t), 16, 0, 0);
        }
    }
#else
    {
        const float4* src = reinterpret_cast<const float4*>(
            feat + ((size_t)b * CHANNELS + c) * PLANE);
#pragma unroll
        for (int i = 0; i < 4; ++i)
            reinterpret_cast<float4*>(pl)[i * 256 + t] = src[i * 256 + t];
    }
#endif

    __syncthreads();   // single barrier: wsum visible + staging drained

    // 5. Cross-wave prefix + bucket offsets (from packed wave totals).
    int tot0 = 0, tot1 = 0, tot2 = 0, tot3 = 0, wpre = 0;
#pragma unroll
    for (int w = 0; w < 4; ++w) {
        unsigned long long v = wsum[w];
        if (w < wv) wpre += (int)((v >> (16 * b)) & 0xFFFF);
        tot0 += (int)( v        & 0xFFFF);
        tot1 += (int)((v >> 16) & 0xFFFF);
        tot2 += (int)((v >> 32) & 0xFFFF);
        tot3 += (int)((v >> 48) & 0xFFFF);
    }
    int off = 0;
    if (b > 0) off += tot0;
    if (b > 1) off += tot1;
    if (b > 2) off += tot2;
    (void)tot3;

    int slot = off + wpre + (inc - my);    // exclusive slot base, n-stable

    // 6. Region sums from LDS; contiguous writes (full sectors, no RMW).
#pragma unroll
    for (int j = 0; j < 4; ++j) {
        if (bj[j] == b) {
            float v = region_avg(pl, hs[j], he[j], wss[j], wee[j]);
            ws[(size_t)c * NUM_ROIS + slot] = v;
            if (c == 0) perm[slot] = 4 * t + j;
            ++slot;
        }
    }
}

// ws[1029][1024-compacted] -> out[n][1029] via perm[k]=n. 32x32 tiles,
// 33-pad LDS. Reads coalesced along k; writes are 128 B runs along c at
// row perm[k] (sector-complete -> no RMW amplification).
__global__ __launch_bounds__(256)
void transpose_cn_perm(const float* __restrict__ ws,
                       const int* __restrict__ perm,
                       float* __restrict__ out) {
    __shared__ float tile[32][33];
    const int c0 = blockIdx.y * 32;
    const int k0 = blockIdx.x * 32;
    const int tx = threadIdx.x & 31;
    const int ty = threadIdx.x >> 5;              // 0..7

#pragma unroll
    for (int i = 0; i < 32; i += 8) {
        const int cc = c0 + ty + i;
        if (cc < CHANNELS)
            tile[ty + i][tx] = ws[(size_t)cc * NUM_ROIS + (k0 + tx)];
    }
    __syncthreads();
#pragma unroll
    for (int i = 0; i < 32; i += 8) {
        const int nn = perm[k0 + ty + i];         // wave-uniform L2 broadcast
        const int cc = c0 + tx;
        if (cc < CHANNELS)
            out[(size_t)nn * CHANNELS + cc] = tile[tx][ty + i];
    }
}

// ---------- fallback path (R1-verified, no workspace) ----------
__global__ __launch_bounds__(1024)
void psroi_lds_direct(const float* __restrict__ feat,
                      const float* __restrict__ rois,
                      float* __restrict__ dst) {
    const int c  = blockIdx.x;
    const int pw = c % 7;
    const int ph = (c / 7) % 7;
    const int t  = threadIdx.x;

    __shared__ float pl[4 * PLANE];

    const float* r = rois + (size_t)t * 5;
    float r0 = r[0], r1 = r[1], r2 = r[2], r3 = r[3], r4 = r[4];

#pragma unroll
    for (int bb = 0; bb < 4; ++bb) {
        const float4* src = reinterpret_cast<const float4*>(
            feat + ((size_t)bb * CHANNELS + c) * PLANE);
        reinterpret_cast<float4*>(pl + bb * PLANE)[t] = src[t];
    }

    RoiGeom g = roi_geom_v(r0, r1, r2, r3, r4);
    int hs, he, wss, wee;
    bin_bounds(g, ph, pw, hs, he, wss, wee);

    __syncthreads();

    float v = region_avg(pl + g.b * PLANE, hs, he, wss, wee);
    dst[(size_t)t * CHANNELS + c] = v;
}

extern "C" void kernel_launch(void* const* d_in, const int* in_sizes, int n_in,
                              void* d_out, int out_size, void* d_ws, size_t ws_size,
                              hipStream_t stream) {
    const float* feat = (const float*)d_in[0];
    const float* rois = (const float*)d_in[1];
    float* out = (float*)d_out;

    const size_t need = sizeof(float) * ((size_t)CHANNELS * NUM_ROIS + NUM_ROIS);
    if (d_ws != nullptr && ws_size >= need) {
        float* wsp  = (float*)d_ws;
        int*   perm = (int*)(wsp + (size_t)CHANNELS * NUM_ROIS);
        psroi_bucket<<<CHANNELS * 4, 256, 0, stream>>>(feat, rois, wsp, perm);
        transpose_cn_perm<<<dim3(NUM_ROIS / 32, (CHANNELS + 31) / 32), 256, 0, stream>>>(
            wsp, perm, out);
    } else {
        psroi_lds_direct<<<CHANNELS, 1024, 0, stream>>>(feat, rois, out);
    }
}

// Round 5
// 103.275 us; speedup vs baseline: 1.0680x; 1.0680x over previous
//
#include <hip/hip_runtime.h>
#include <math.h>

#define POOLED      7
#define OUTPUT_DIM  21
#define GROUP       7
#define CHANNELS    (OUTPUT_DIM * GROUP * GROUP)   // 1029
#define FH          64
#define FW          64
#define PLANE       (FH * FW)                      // 4096 floats, 16 KB
#define NUM_ROIS    1024
#define SCALE       0.0625f
#define NTHR        512

// Opaque VGPR pin: blocks FMA contraction (hipcc -ffp-contract=fast ignores
// `#pragma clang fp contract(off)`). CORRECTNESS-CRITICAL: the golden's
// boundary chain is f32, separately rounded, with bin = roi * RN(1/7)
// (reciprocal multiply) — verified round 10, absmax 3.9e-3. Do not change.
__device__ __forceinline__ float freeze(float x) {
    __asm__ volatile("" : "+v"(x));
    return x;
}

// ---- frozen boundary chain, value form (ops identical to r10-verified) ----
struct RoiGeom { int b; float start_h, start_w, bin_h, bin_w; };

__device__ __forceinline__ RoiGeom roi_geom_v(float r0, float r1, float r2,
                                              float r3, float r4) {
    RoiGeom g;
    g.b = (int)r0;
    float start_w = rintf(r1) * SCALE;            // np.round = half-even
    float start_h = rintf(r2) * SCALE;
    float end_w   = rintf(r3 + 1.0f) * SCALE;
    float end_h   = rintf(r4 + 1.0f) * SCALE;
    float roi_w = fmaxf(end_w - start_w, 0.1f);
    float roi_h = fmaxf(end_h - start_h, 0.1f);
    const float inv7 = 1.0f / 7.0f;               // RN(1/7)
    g.bin_h = freeze(roi_h * inv7);               // reciprocal multiply
    g.bin_w = freeze(roi_w * inv7);
    g.start_h = start_h;
    g.start_w = start_w;
    return g;
}

__device__ __forceinline__ void bin_bounds(const RoiGeom& g, int ph, int pw,
                                           int& hs, int& he, int& ws, int& we) {
    float mh0 = freeze((float)ph * g.bin_h);      // separate mul, then add
    float mh1 = freeze((float)(ph + 1) * g.bin_h);
    float mw0 = freeze((float)pw * g.bin_w);
    float mw1 = freeze((float)(pw + 1) * g.bin_w);

    float hs_f = floorf(mh0 + g.start_h);
    float he_f = ceilf (mh1 + g.start_h);
    float ws_f = floorf(mw0 + g.start_w);
    float we_f = ceilf (mw1 + g.start_w);

    hs = (int)fminf(fmaxf(hs_f, 0.0f), (float)FH);
    he = (int)fminf(fmaxf(he_f, 0.0f), (float)FH);
    ws = (int)fminf(fmaxf(ws_f, 0.0f), (float)FW);
    we = (int)fminf(fmaxf(we_f, 0.0f), (float)FW);
}

__device__ __forceinline__ float region_avg(const float* __restrict__ plane,
                                            int hs, int he, int ws, int we) {
    float s = 0.0f;
    for (int h = hs; h < he; ++h) {
        const float* row = plane + h * FW;
        for (int w = ws; w < we; ++w) s += row[w];
    }
    int area = (he - hs) * (we - ws);
    return (area <= 0) ? 0.0f : s / (float)area;
}

__device__ __forceinline__ int sel4(int b, int x0, int x1, int x2, int x3) {
    return b == 0 ? x0 : b == 1 ? x1 : b == 2 ? x2 : x3;
}

// DOUBLE-BUFFERED BIN-MAJOR (round 16). R1's structure phase-locks: 2
// blocks/CU, every block stages (HBM busy, ALU idle) then computes (HBM
// idle) => ~stage+compute ~= 20 us vs the 10.7 us fetch floor. R4's grid
// split fixed occupancy but replicated the 1024-ROI scan 4116x (regressed).
// Here: block = channel (1029 blocks, scan once), 512 threads, two 16 KB
// plane buffers. Prologue: packed shfl scan partitions ROIs by batch
// (R4-verified machinery), packs each ROI's clamped bounds into a u32 at
// its compacted slot in LDS. Then 4 sub-phases: issue stage(plane b+1)
// into the idle buffer, compute bucket b with PACKED lanes (thread k ->
// slot off_b+k: zero batch divergence, coalesced ws writes), barrier.
// Staging latency hides under compute continuously instead of alternating.
// LDS 36 KB + 512 thr -> 4 blocks/CU (32 waves/CU), grid fits in one
// round (1024 resident). Numerics: region_avg order identical to R1.
__global__ __launch_bounds__(NTHR, 8)
void psroi_dbuf(const float* __restrict__ feat,
                const float* __restrict__ rois,
                float* __restrict__ ws,
                int* __restrict__ perm) {
    const int c  = blockIdx.x;            // 0..1028
    const int pw = c % 7;
    const int ph = (c / 7) % 7;
    const int t  = threadIdx.x;           // 0..511
    const int ln = t & 63;
    const int wv = t >> 6;                // 0..7

    __shared__ float buf0[PLANE];         // 16 KB
    __shared__ float buf1[PLANE];         // 16 KB
    __shared__ unsigned int bnds[NUM_ROIS];   // 4 KB packed bounds at slot
    __shared__ unsigned long long wsum[8];

    // 1. ROI loads FIRST (in-order vmcnt retire: uses of rr then don't wait
    //    on the staging loads issued after them).
    float rr[2][5];
#pragma unroll
    for (int j = 0; j < 2; ++j) {
        const float* r = rois + (size_t)(2 * t + j) * 5;
#pragma unroll
        for (int q = 0; q < 5; ++q) rr[j][q] = r[q];
    }

    // 2. Kick off plane-0 staging (fire-and-forget into buf0).
#if defined(__has_builtin) && __has_builtin(__builtin_amdgcn_global_load_lds)
    typedef const void __attribute__((address_space(1)))* gas_t;
    typedef void __attribute__((address_space(3)))*       las_t;
#define STAGE(dst, pidx)                                                        \
    do {                                                                        \
        const float* s0_ = feat + ((size_t)(pidx) * CHANNELS + c) * PLANE       \
                                + 4 * (size_t)t;                                \
        __builtin_amdgcn_global_load_lds((gas_t)s0_, (las_t)((dst) + 4 * t),    \
                                         16, 0, 0);                             \
        __builtin_amdgcn_global_load_lds((gas_t)(s0_ + 2048),                   \
                                         (las_t)((dst) + 2048 + 4 * t), 16, 0, 0); \
    } while (0)
#else
#define STAGE(dst, pidx)                                                        \
    do {                                                                        \
        const float4* s4_ = reinterpret_cast<const float4*>(                    \
            feat + ((size_t)(pidx) * CHANNELS + c) * PLANE);                    \
        reinterpret_cast<float4*>(dst)[t]       = s4_[t];                       \
        reinterpret_cast<float4*>(dst)[512 + t] = s4_[512 + t];                 \
    } while (0)
#endif
    STAGE(buf0, 0);

    // 3. Per-wave packed scan (counts of 4 buckets in 16-bit fields).
    const int b0 = ((int)rr[0][0]) & 3;
    const int b1 = ((int)rr[1][0]) & 3;
    unsigned long long pk = (1ull << (16 * b0)) + (1ull << (16 * b1));
    unsigned long long inc = pk;
#pragma unroll
    for (int d = 1; d < 64; d <<= 1) {
        unsigned long long u = __shfl_up(inc, d, 64);
        if (ln >= d) inc += u;
    }
    const unsigned long long excl = inc - pk;     // per-bucket lane prefix
    if (ln == 63) wsum[wv] = inc;                 // wave totals (packed)

    // 4. Geometry for both ROIs -> packed u32 bounds (register-only).
    unsigned int pb[2];
#pragma unroll
    for (int j = 0; j < 2; ++j) {
        RoiGeom g = roi_geom_v(rr[j][0], rr[j][1], rr[j][2], rr[j][3], rr[j][4]);
        int hs, he, wss, wee;
        bin_bounds(g, ph, pw, hs, he, wss, wee);
        pb[j] = (unsigned)hs | ((unsigned)he << 7) |
                ((unsigned)wss << 14) | ((unsigned)wee << 21);
    }

    __syncthreads();   // wsum visible (also drains plane-0 staging)

    // 5. Cross-wave totals / prefixes -> compacted slots; bounds -> LDS.
    int tot0 = 0, tot1 = 0, tot2 = 0, tot3 = 0;
    int wp0 = 0, wp1 = 0, wp2 = 0, wp3 = 0;
#pragma unroll
    for (int w = 0; w < 8; ++w) {
        unsigned long long v = wsum[w];
        int a0 = (int)( v        & 0xFFFF);
        int a1 = (int)((v >> 16) & 0xFFFF);
        int a2 = (int)((v >> 32) & 0xFFFF);
        int a3 = (int)((v >> 48) & 0xFFFF);
        tot0 += a0; tot1 += a1; tot2 += a2; tot3 += a3;
        if (w < wv) { wp0 += a0; wp1 += a1; wp2 += a2; wp3 += a3; }
    }
    const int off1 = tot0, off2 = tot0 + tot1, off3 = tot0 + tot1 + tot2;

    const int slot0 = sel4(b0, 0, off1, off2, off3) + sel4(b0, wp0, wp1, wp2, wp3)
                    + (int)((excl >> (16 * b0)) & 0xFFFF);
    const int slot1 = sel4(b1, 0, off1, off2, off3) + sel4(b1, wp0, wp1, wp2, wp3)
                    + (int)((excl >> (16 * b1)) & 0xFFFF) + (b1 == b0 ? 1 : 0);

    bnds[slot0] = pb[0];
    bnds[slot1] = pb[1];
    if (c == 0) { perm[slot0] = 2 * t; perm[slot1] = 2 * t + 1; }

    __syncthreads();   // bnds visible

    // 6. Sub-phases: stage plane b+1 || compute bucket b (packed lanes).
#pragma unroll
    for (int b = 0; b < 4; ++b) {
        const float* cur = (b & 1) ? buf1 : buf0;
        float*       nxt = (b & 1) ? buf0 : buf1;
        if (b < 3) STAGE(nxt, b + 1);             // fire-and-forget

        const int offb = (b == 0) ? 0 : (b == 1) ? off1 : (b == 2) ? off2 : off3;
        const int cntb = (b == 0) ? tot0 : (b == 1) ? tot1 : (b == 2) ? tot2 : tot3;

        for (int k = t; k < cntb; k += NTHR) {
            const unsigned int p = bnds[offb + k];
            float v = region_avg(cur, (int)(p & 127), (int)((p >> 7) & 127),
                                 (int)((p >> 14) & 127), (int)((p >> 21) & 127));
            ws[(size_t)c * NUM_ROIS + offb + k] = v;   // coalesced, full sectors
        }
        __syncthreads();   // drains staging of b+1; frees cur for b+2 restage
    }
#undef STAGE
}

// ws[1029][1024-compacted] -> out[n][1029] via perm[k]=n. 32x32 tiles,
// 33-pad LDS. R4-verified byte-for-byte.
__global__ __launch_bounds__(256)
void transpose_cn_perm(const float* __restrict__ ws,
                       const int* __restrict__ perm,
                       float* __restrict__ out) {
    __shared__ float tile[32][33];
    const int c0 = blockIdx.y * 32;
    const int k0 = blockIdx.x * 32;
    const int tx = threadIdx.x & 31;
    const int ty = threadIdx.x >> 5;              // 0..7

#pragma unroll
    for (int i = 0; i < 32; i += 8) {
        const int cc = c0 + ty + i;
        if (cc < CHANNELS)
            tile[ty + i][tx] = ws[(size_t)cc * NUM_ROIS + (k0 + tx)];
    }
    __syncthreads();
#pragma unroll
    for (int i = 0; i < 32; i += 8) {
        const int nn = perm[k0 + ty + i];         // wave-uniform L2 broadcast
        const int cc = c0 + tx;
        if (cc < CHANNELS)
            out[(size_t)nn * CHANNELS + cc] = tile[tx][ty + i];
    }
}

// ---------- fallback path (R1-verified, no workspace) ----------
__global__ __launch_bounds__(1024)
void psroi_lds_direct(const float* __restrict__ feat,
                      const float* __restrict__ rois,
                      float* __restrict__ dst) {
    const int c  = blockIdx.x;
    const int pw = c % 7;
    const int ph = (c / 7) % 7;
    const int t  = threadIdx.x;

    __shared__ float pl[4 * PLANE];

    const float* r = rois + (size_t)t * 5;
    float r0 = r[0], r1 = r[1], r2 = r[2], r3 = r[3], r4 = r[4];

#pragma unroll
    for (int bb = 0; bb < 4; ++bb) {
        const float4* src = reinterpret_cast<const float4*>(
            feat + ((size_t)bb * CHANNELS + c) * PLANE);
        reinterpret_cast<float4*>(pl + bb * PLANE)[t] = src[t];
    }

    RoiGeom g = roi_geom_v(r0, r1, r2, r3, r4);
    int hs, he, wss, wee;
    bin_bounds(g, ph, pw, hs, he, wss, wee);

    __syncthreads();

    float v = region_avg(pl + g.b * PLANE, hs, he, wss, wee);
    dst[(size_t)t * CHANNELS + c] = v;
}

extern "C" void kernel_launch(void* const* d_in, const int* in_sizes, int n_in,
                              void* d_out, int out_size, void* d_ws, size_t ws_size,
                              hipStream_t stream) {
    const float* feat = (const float*)d_in[0];
    const float* rois = (const float*)d_in[1];
    float* out = (float*)d_out;

    const size_t need = sizeof(float) * ((size_t)CHANNELS * NUM_ROIS + NUM_ROIS);
    if (d_ws != nullptr && ws_size >= need) {
        float* wsp  = (float*)d_ws;
        int*   perm = (int*)(wsp + (size_t)CHANNELS * NUM_ROIS);
        psroi_dbuf<<<CHANNELS, NTHR, 0, stream>>>(feat, rois, wsp, perm);
        transpose_cn_perm<<<dim3(NUM_ROIS / 32, (CHANNELS + 31) / 32), 256, 0, stream>>>(
            wsp, perm, out);
    } else {
        psroi_lds_direct<<<CHANNELS, 1024, 0, stream>>>(feat, rois, out);
    }
}